// Round 2
// baseline (152.787 us; speedup 1.0000x reference)
//
#include <hip/hip_runtime.h>
#include <hip/hip_bf16.h>

// EpiLinear: epinet (2080->512->32, z-contract) + prior ensemble (32x [1024->5->5->1], z-contract)
// B=2048, NZ=8, ND=32, STATE=HIDDEN=1024, EPI_HIDDEN=512. All inputs/outputs FP32.
//
//  - hx[b,:] = [x|feature] @ Wep1[0:2048,:] is shared across the 8 z-samples (ReLU comes after
//    the sum), so the big GEMM is [2048x2048]x[2048x768] instead of [16384x2080]x[2080x512].
//  - Inputs converted fp32->bf16 in ws (A, WT); GEMM in bf16 MFMA, fp32 accumulate.
//  - Prior layer-1 (32 MLPs, x @ Wp1[e]) folded into the GEMM as columns 512..671 of WT.
//  - GEMM: 128x128 tile, mfma_f32_16x16x32_bf16, global_load_lds width=16, B^T layout,
//    XOR LDS swizzle, split-K=4 (384 blocks).
//  - combine kernel (fp32): prior MLP tail + z-part of epinet layer1 + ReLU + layer2 + fused
//    z-dot of epinet and prior outputs.

typedef __hip_bfloat16 bf16;
typedef __attribute__((ext_vector_type(8))) short short8;   // 8 bf16 = 4 VGPRs (MFMA A/B frag)
typedef __attribute__((ext_vector_type(4))) float f32x4;    // MFMA C/D frag

#define NCOMB 768
#define NSPLIT 4
#define A_BYTES  (2048u * 2048u * 2u)
#define WT_BYTES (768u * 2048u * 2u)

__device__ __forceinline__ void gload_lds16(const bf16* g, bf16* l) {
    __builtin_amdgcn_global_load_lds(
        (const __attribute__((address_space(1))) void*)g,
        (__attribute__((address_space(3))) void*)l, 16, 0, 0);
}

__device__ __forceinline__ short f2bf_bits(float f) {
    bf16 h = __float2bfloat16(f);
    return *reinterpret_cast<short*>(&h);
}

// ---------------------------------------------------------------------------
// A[b][0:1024]=x[b], A[b][1024:2048]=feature[b], fp32 -> bf16. 4 elems/thread.
__global__ __launch_bounds__(256) void prep_a(const float* __restrict__ x,
                                              const float* __restrict__ feat,
                                              bf16* __restrict__ A) {
    int idx = blockIdx.x * 256 + threadIdx.x;   // 1,048,576 threads
    int b = idx >> 9;                           // 512 groups of 4 per row
    int g = idx & 511;
    const float* src = (g < 256) ? (x + (size_t)b * 1024 + g * 4)
                                 : (feat + (size_t)b * 1024 + (g - 256) * 4);
    float4 v = *(const float4*)src;
    short4 p;
    p.x = f2bf_bits(v.x); p.y = f2bf_bits(v.y);
    p.z = f2bf_bits(v.z); p.w = f2bf_bits(v.w);
    *(short4*)(A + (size_t)b * 2048 + g * 4) = p;
}

// ---------------------------------------------------------------------------
// WT[n][k]: n<512 -> Wep1[k][n]; 512<=n<672 -> Wp1[e,k,h] (k<1024) else 0; else 0.
__global__ __launch_bounds__(256) void prep_wt(const float* __restrict__ Wep1,
                                               const float* __restrict__ Wp1,
                                               bf16* __restrict__ WT) {
    int idx = blockIdx.x * 256 + threadIdx.x;   // 768*2048
    int n = idx >> 11;
    int k = idx & 2047;
    float v = 0.f;
    if (n < 512) {
        v = Wep1[(size_t)k * 512 + n];
    } else if (n < 672) {
        int q = n - 512;
        int e = q / 5, h = q - e * 5;
        if (k < 1024) v = Wp1[(size_t)e * 5120 + k * 5 + h];
    }
    WT[idx] = __float2bfloat16(v);
}

// ---------------------------------------------------------------------------
// Gp[s][b][c] = sum_{k in split s (512 wide)} A[b][k] * WT[c][k]
// grid (6, 16, 4), 256 thr = 4 waves (2x2 of 64x64).
__global__ __launch_bounds__(256) void gemm_split(const bf16* __restrict__ A,
                                                  const bf16* __restrict__ WT,
                                                  float* __restrict__ Gp) {
    __shared__ bf16 As[128 * 64];
    __shared__ bf16 Bs[128 * 64];
    const int t    = threadIdx.x;
    const int lane = t & 63;
    const int wv   = t >> 6;
    const int m0 = blockIdx.y * 128;
    const int n0 = blockIdx.x * 128;
    const int kbase = blockIdx.z * 512;
    const int lm = lane & 15;
    const int lq = lane >> 4;
    const int wm = (wv & 1) * 64;
    const int wn = (wv >> 1) * 64;
    f32x4 acc[4][4] = {};

    for (int k0 = 0; k0 < 512; k0 += 64) {
        __syncthreads();   // previous compute done before LDS overwrite
#pragma unroll
        for (int i = 0; i < 4; ++i) {
            int chunk = i * 256 + wv * 64 + lane;   // 16B chunk id, [0,1024)
            int row   = chunk >> 3;                 // tile row 0..127
            int gph   = chunk & 7;                  // physical 8-elem group in LDS row
            int gda   = gph ^ (row & 7);            // XOR swizzle: data group stored at gph
            gload_lds16(A  + (size_t)(m0 + row) * 2048 + kbase + k0 + gda * 8,
                        As + (i * 256 + wv * 64) * 8);   // wave-uniform LDS base
            gload_lds16(WT + (size_t)(n0 + row) * 2048 + kbase + k0 + gda * 8,
                        Bs + (i * 256 + wv * 64) * 8);
        }
        __syncthreads();   // drains vmcnt: tiles ready
#pragma unroll
        for (int kk = 0; kk < 64; kk += 32) {
            short8 af[4], bfr[4];
#pragma unroll
            for (int i2 = 0; i2 < 4; ++i2) {
                int ra = wm + i2 * 16 + lm;
                int ga = ((kk >> 3) + lq) ^ (ra & 7);
                af[i2] = *(const short8*)(As + ra * 64 + ga * 8);
                int rb = wn + i2 * 16 + lm;
                int gb = ((kk >> 3) + lq) ^ (rb & 7);
                bfr[i2] = *(const short8*)(Bs + rb * 64 + gb * 8);
            }
#pragma unroll
            for (int mi = 0; mi < 4; ++mi)
#pragma unroll
                for (int ni = 0; ni < 4; ++ni)
                    acc[mi][ni] = __builtin_amdgcn_mfma_f32_16x16x32_bf16(
                        af[mi], bfr[ni], acc[mi][ni], 0, 0, 0);
        }
    }
    // C/D layout: col = lane&15, row = (lane>>4)*4 + r  [m89/m91-verified]
    float* Gs = Gp + (size_t)blockIdx.z * 2048 * NCOMB;
#pragma unroll
    for (int mi = 0; mi < 4; ++mi)
#pragma unroll
        for (int ni = 0; ni < 4; ++ni) {
            int row = m0 + wm + mi * 16 + lq * 4;
            int col = n0 + wn + ni * 16 + lm;
#pragma unroll
            for (int r = 0; r < 4; ++r)
                Gs[(size_t)(row + r) * NCOMB + col] = acc[mi][ni][r];
        }
}

// ---------------------------------------------------------------------------
// combine: one block per b (2048 blocks, 256 threads). All fp32.
__global__ __launch_bounds__(256) void combine(const float* __restrict__ Gp,
                                               const float* __restrict__ z,
                                               const float* __restrict__ Wep1,
                                               const float* __restrict__ Wep2,
                                               const float* __restrict__ bep1,
                                               const float* __restrict__ bep2,
                                               const float* __restrict__ bp1,
                                               const float* __restrict__ Wp2,
                                               const float* __restrict__ bp2,
                                               const float* __restrict__ Wp3,
                                               const float* __restrict__ bp3,
                                               float* __restrict__ out) {
    __shared__ float zf[8][32];
    __shared__ float h1s[160];
    __shared__ float h2s[160];
    __shared__ float ps[32];
    __shared__ float hbuf[8][512];
    const int b = blockIdx.x;
    const int t = threadIdx.x;
    const size_t SSTR = (size_t)2048 * NCOMB;
    const float* Gb = Gp + (size_t)b * NCOMB;

    // z -> LDS
    zf[t >> 5][t & 31] = z[b * 256 + t];
    // prior h1 = relu(sum_s G[s][:,512+t] + bp1)
    if (t < 160) {
        float v = Gb[512 + t] + Gb[SSTR + 512 + t] + Gb[2 * SSTR + 512 + t]
                + Gb[3 * SSTR + 512 + t] + bp1[t];
        h1s[t] = fmaxf(v, 0.f);
    }
    __syncthreads();
    // prior h2 = relu(h1 @ Wp2[e] + bp2)
    if (t < 160) {
        int e = t / 5, g = t - e * 5;
        float a = bp2[t];
#pragma unroll
        for (int h = 0; h < 5; ++h)
            a += h1s[e * 5 + h] * Wp2[e * 25 + h * 5 + g];
        h2s[t] = fmaxf(a, 0.f);
    }
    __syncthreads();
    // p[e] = h2 @ Wp3[e] + bp3
    if (t < 32) {
        float a = bp3[t];
#pragma unroll
        for (int g = 0; g < 5; ++g)
            a += h2s[t * 5 + g] * Wp3[t * 5 + g];
        ps[t] = a;
    }
    // epinet: h[n][c] = relu(hx[c] + z[n]@Wz[:,c] + bep1[c]), 2 cols/thread
    {
        const float* Wz = Wep1 + (size_t)2048 * 512;   // rows 2048..2079
        const int c0 = t, c1 = t + 256;
        float s0[8] = {}, s1[8] = {};
#pragma unroll 4
        for (int k = 0; k < 32; ++k) {
            float w0 = Wz[k * 512 + c0];
            float w1 = Wz[k * 512 + c1];
#pragma unroll
            for (int n = 0; n < 8; ++n) {
                float zv = zf[n][k];   // LDS broadcast
                s0[n] += zv * w0;
                s1[n] += zv * w1;
            }
        }
        float base0 = Gb[c0] + Gb[SSTR + c0] + Gb[2 * SSTR + c0] + Gb[3 * SSTR + c0] + bep1[c0];
        float base1 = Gb[c1] + Gb[SSTR + c1] + Gb[2 * SSTR + c1] + Gb[3 * SSTR + c1] + bep1[c1];
#pragma unroll
        for (int n = 0; n < 8; ++n) {
            hbuf[n][c0] = fmaxf(base0 + s0[n], 0.f);
            hbuf[n][c1] = fmaxf(base1 + s1[n], 0.f);
        }
    }
    __syncthreads();
    // layer2 + fused z-dot (epinet + prior): res[b,n] = sum_j (out2[n,j] + p[j]) * z[n,j]
    {
        const int n = t >> 5, j = t & 31;
        float o = bep2[j];
        for (int c = 0; c < 512; ++c)
            o += hbuf[n][c] * Wep2[c * 32 + j];
        float val = (o + ps[j]) * zf[n][j];
#pragma unroll
        for (int off = 16; off > 0; off >>= 1)
            val += __shfl_xor(val, off, 64);   // reduce within each 32-lane j-group
        if (j == 0) out[b * 8 + n] = val;
    }
}

// ---------------------------------------------------------------------------
extern "C" void kernel_launch(void* const* d_in, const int* in_sizes, int n_in,
                              void* d_out, int out_size, void* d_ws, size_t ws_size,
                              hipStream_t stream) {
    const float* x    = (const float*)d_in[0];
    const float* feat = (const float*)d_in[1];
    const float* z    = (const float*)d_in[2];
    const float* Wep1 = (const float*)d_in[3];
    const float* bep1 = (const float*)d_in[4];
    const float* Wep2 = (const float*)d_in[5];
    const float* bep2 = (const float*)d_in[6];
    const float* Wp1  = (const float*)d_in[7];
    const float* bp1  = (const float*)d_in[8];
    const float* Wp2  = (const float*)d_in[9];
    const float* bp2  = (const float*)d_in[10];
    const float* Wp3  = (const float*)d_in[11];
    const float* bp3  = (const float*)d_in[12];
    float* out = (float*)d_out;

    char* ws  = (char*)d_ws;
    bf16* A   = (bf16*)ws;                            // 8,388,608 B
    bf16* WT  = (bf16*)(ws + A_BYTES);                // 3,145,728 B
    float* Gp = (float*)(ws + A_BYTES + WT_BYTES);    // 4*2048*768*4 = 25,165,824 B

    prep_a<<<4096, 256, 0, stream>>>(x, feat, A);
    prep_wt<<<6144, 256, 0, stream>>>(Wep1, Wp1, WT);
    gemm_split<<<dim3(6, 16, NSPLIT), 256, 0, stream>>>(A, WT, Gp);
    combine<<<2048, 256, 0, stream>>>(Gp, z, Wep1, Wep2, bep1, bep2,
                                      bp1, Wp2, bp2, Wp3, bp3, out);
}

// Round 3
// 126.074 us; speedup vs baseline: 1.2119x; 1.2119x over previous
//
#include <hip/hip_runtime.h>
#include <hip/hip_bf16.h>

// EpiLinear: epinet (2080->512->32, z-contract) + prior ensemble (32x [1024->5->5->1], z-contract)
// B=2048, NZ=8, ND=32, STATE=HIDDEN=1024, EPI_HIDDEN=512. All inputs/outputs FP32.
//
//  - hx[b,:] = [x|feature] @ Wep1[0:2048,:] shared across the 8 z-samples -> big GEMM is
//    [2048x2048]x[2048x768] (prior layer-1 folded in as cols 512..671).
//  - combine (this round): MFMA-ized. 4 b's per block (32 rows of (b,n)); zW = z@Wz and
//    layer-2 h@Wep2 via 16x16x32 bf16 MFMA with XOR-swizzled LDS; prior tail + final
//    z-contraction in fp32 VALU. Wz/Wep2 staged+transposed from original fp32 inputs.
//  - prep_wt: 64x64 LDS-tiled transpose for the Wep1 part (coalesced reads AND writes).

typedef __hip_bfloat16 bf16;
typedef __attribute__((ext_vector_type(8))) short short8;   // 8 bf16 = 4 VGPRs (MFMA A/B frag)
typedef __attribute__((ext_vector_type(4))) float f32x4;    // MFMA C/D frag

#define NCOMB 768
#define NSPLIT 4
#define A_BYTES  (2048u * 2048u * 2u)
#define WT_BYTES (768u * 2048u * 2u)

__device__ __forceinline__ void gload_lds16(const bf16* g, bf16* l) {
    __builtin_amdgcn_global_load_lds(
        (const __attribute__((address_space(1))) void*)g,
        (__attribute__((address_space(3))) void*)l, 16, 0, 0);
}

__device__ __forceinline__ short f2bf_bits(float f) {
    bf16 h = __float2bfloat16(f);
    return *reinterpret_cast<short*>(&h);
}

// ---------------------------------------------------------------------------
// A[b][0:1024]=x[b], A[b][1024:2048]=feature[b], fp32 -> bf16. 4 elems/thread.
__global__ __launch_bounds__(256) void prep_a(const float* __restrict__ x,
                                              const float* __restrict__ feat,
                                              bf16* __restrict__ A) {
    int idx = blockIdx.x * 256 + threadIdx.x;
    int b = idx >> 9;
    int g = idx & 511;
    const float* src = (g < 256) ? (x + (size_t)b * 1024 + g * 4)
                                 : (feat + (size_t)b * 1024 + (g - 256) * 4);
    float4 v = *(const float4*)src;
    short4 p;
    p.x = f2bf_bits(v.x); p.y = f2bf_bits(v.y);
    p.z = f2bf_bits(v.z); p.w = f2bf_bits(v.w);
    *(short4*)(A + (size_t)b * 2048 + g * 4) = p;
}

// ---------------------------------------------------------------------------
// WT[n][k]: n<512 -> Wep1[k][n] (tiled transpose); 512<=n<672 -> Wp1[e,k,h] (k<1024); else 0.
// Blocks [0,256): 64x64 transpose tiles. Blocks [256,2304): scalar region n in [512,768).
__global__ __launch_bounds__(256) void prep_wt(const float* __restrict__ Wep1,
                                               const float* __restrict__ Wp1,
                                               bf16* __restrict__ WT) {
    const int t = threadIdx.x;
    if (blockIdx.x < 256) {
        __shared__ short tile[64 * 66];   // [n-local][k-local], stride 66 (2-way banks = free)
        int kt = blockIdx.x >> 3, nt = blockIdx.x & 7;
        int k0 = kt * 64, n0 = nt * 64;
        int r = t >> 4, cq = t & 15;
#pragma unroll
        for (int i = 0; i < 4; ++i) {
            int rr = r + i * 16;   // k-local
            float4 v = *(const float4*)(Wep1 + (size_t)(k0 + rr) * 512 + n0 + cq * 4);
            tile[(cq * 4 + 0) * 66 + rr] = f2bf_bits(v.x);
            tile[(cq * 4 + 1) * 66 + rr] = f2bf_bits(v.y);
            tile[(cq * 4 + 2) * 66 + rr] = f2bf_bits(v.z);
            tile[(cq * 4 + 3) * 66 + rr] = f2bf_bits(v.w);
        }
        __syncthreads();
#pragma unroll
        for (int i = 0; i < 2; ++i) {
            int ch = i * 256 + t;          // 512 chunks of 8
            int nr = ch >> 3, kc = ch & 7;
            short8 s = *(const short8*)(tile + nr * 66 + kc * 8);
            *(short8*)(WT + (size_t)(n0 + nr) * 2048 + k0 + kc * 8) = s;
        }
    } else {
        int local = (blockIdx.x - 256) * 256 + t;   // 524288 elems
        int n = 512 + (local >> 11);
        int k = local & 2047;
        float v = 0.f;
        if (n < 672) {
            int q = n - 512;
            int e = q / 5, h = q - e * 5;
            if (k < 1024) v = Wp1[(size_t)e * 5120 + k * 5 + h];
        }
        WT[(size_t)n * 2048 + k] = __float2bfloat16(v);
    }
}

// ---------------------------------------------------------------------------
// Gp[s][b][c] = sum_{k in split s (512 wide)} A[b][k] * WT[c][k]
__global__ __launch_bounds__(256) void gemm_split(const bf16* __restrict__ A,
                                                  const bf16* __restrict__ WT,
                                                  float* __restrict__ Gp) {
    __shared__ bf16 As[128 * 64];
    __shared__ bf16 Bs[128 * 64];
    const int t    = threadIdx.x;
    const int lane = t & 63;
    const int wv   = t >> 6;
    const int m0 = blockIdx.y * 128;
    const int n0 = blockIdx.x * 128;
    const int kbase = blockIdx.z * 512;
    const int lm = lane & 15;
    const int lq = lane >> 4;
    const int wm = (wv & 1) * 64;
    const int wn = (wv >> 1) * 64;
    f32x4 acc[4][4] = {};

    for (int k0 = 0; k0 < 512; k0 += 64) {
        __syncthreads();
#pragma unroll
        for (int i = 0; i < 4; ++i) {
            int chunk = i * 256 + wv * 64 + lane;
            int row   = chunk >> 3;
            int gph   = chunk & 7;
            int gda   = gph ^ (row & 7);
            gload_lds16(A  + (size_t)(m0 + row) * 2048 + kbase + k0 + gda * 8,
                        As + (i * 256 + wv * 64) * 8);
            gload_lds16(WT + (size_t)(n0 + row) * 2048 + kbase + k0 + gda * 8,
                        Bs + (i * 256 + wv * 64) * 8);
        }
        __syncthreads();
#pragma unroll
        for (int kk = 0; kk < 64; kk += 32) {
            short8 af[4], bfr[4];
#pragma unroll
            for (int i2 = 0; i2 < 4; ++i2) {
                int ra = wm + i2 * 16 + lm;
                int ga = ((kk >> 3) + lq) ^ (ra & 7);
                af[i2] = *(const short8*)(As + ra * 64 + ga * 8);
                int rb = wn + i2 * 16 + lm;
                int gb = ((kk >> 3) + lq) ^ (rb & 7);
                bfr[i2] = *(const short8*)(Bs + rb * 64 + gb * 8);
            }
#pragma unroll
            for (int mi = 0; mi < 4; ++mi)
#pragma unroll
                for (int ni = 0; ni < 4; ++ni)
                    acc[mi][ni] = __builtin_amdgcn_mfma_f32_16x16x32_bf16(
                        af[mi], bfr[ni], acc[mi][ni], 0, 0, 0);
        }
    }
    float* Gs = Gp + (size_t)blockIdx.z * 2048 * NCOMB;
#pragma unroll
    for (int mi = 0; mi < 4; ++mi)
#pragma unroll
        for (int ni = 0; ni < 4; ++ni) {
            int row = m0 + wm + mi * 16 + lq * 4;
            int col = n0 + wn + ni * 16 + lm;
#pragma unroll
            for (int r = 0; r < 4; ++r)
                Gs[(size_t)(row + r) * NCOMB + col] = acc[mi][ni][r];
        }
}

// ---------------------------------------------------------------------------
// combine: 512 blocks x 256 threads; block handles b in [bg*4, bg*4+4), rows r = bi*8+n (32).
__global__ __launch_bounds__(256) void combine(const float* __restrict__ Gp,
                                               const float* __restrict__ z,
                                               const float* __restrict__ Wep1,
                                               const float* __restrict__ Wep2,
                                               const float* __restrict__ bep1,
                                               const float* __restrict__ bep2,
                                               const float* __restrict__ bp1,
                                               const float* __restrict__ Wp2,
                                               const float* __restrict__ bp2,
                                               const float* __restrict__ Wp3,
                                               const float* __restrict__ bp3,
                                               float* __restrict__ out) {
    __shared__ float zf[1024];         // [r=32][k=32] fp32
    __shared__ short zbf[1024];        // [r][k] bf16, A-frag layout (k contig)
    __shared__ float hxs[4 * 512];     // [bi][c] split-summed + bep1
    __shared__ float h1s[640];         // [bi][160]
    __shared__ float h2s[640];
    __shared__ float ps[128];          // [bi][32]
    __shared__ short WzB[256 * 32];    // [c_h][k] bf16, swizzled (zW B-frags)
    __shared__ short W2B[32 * 256];    // [j][c_h] bf16, swizzled (layer-2 B-frags)
    __shared__ short hB[32 * 256];     // [r][c_h] bf16, swizzled (layer-2 A-frags)
    __shared__ float o2s[1024];        // [r][j]
    const int t = threadIdx.x, bg = blockIdx.x;
    const int lane = t & 63, wv = t >> 6;
    const int lm = lane & 15, lq = lane >> 4;
    const int mt = wv & 1;             // m-tile (rows mt*16..+16) for both MFMA phases
    const int jt = wv >> 1;            // layer-2 n-tile / zW n-range selector
    const size_t SSTR = (size_t)2048 * NCOMB;

    // ---- phase 0: z, hx split-sums, prior h1 ----
    {
        float4 v = *(const float4*)(z + (size_t)bg * 1024 + t * 4);
        zf[t * 4 + 0] = v.x; zf[t * 4 + 1] = v.y; zf[t * 4 + 2] = v.z; zf[t * 4 + 3] = v.w;
        zbf[t * 4 + 0] = f2bf_bits(v.x); zbf[t * 4 + 1] = f2bf_bits(v.y);
        zbf[t * 4 + 2] = f2bf_bits(v.z); zbf[t * 4 + 3] = f2bf_bits(v.w);
    }
#pragma unroll
    for (int g = 0; g < 2; ++g) {
        int q = g * 256 + t;               // 512 quads: bi(4) x cq(128)
        int bi = q >> 7, cq = q & 127;
        const float* gp = Gp + (size_t)(bg * 4 + bi) * NCOMB + cq * 4;
        float4 s0 = *(const float4*)(gp);
        float4 s1 = *(const float4*)(gp + SSTR);
        float4 s2 = *(const float4*)(gp + 2 * SSTR);
        float4 s3 = *(const float4*)(gp + 3 * SSTR);
        float4 bb = *(const float4*)(bep1 + cq * 4);
        hxs[bi * 512 + cq * 4 + 0] = s0.x + s1.x + s2.x + s3.x + bb.x;
        hxs[bi * 512 + cq * 4 + 1] = s0.y + s1.y + s2.y + s3.y + bb.y;
        hxs[bi * 512 + cq * 4 + 2] = s0.z + s1.z + s2.z + s3.z + bb.z;
        hxs[bi * 512 + cq * 4 + 3] = s0.w + s1.w + s2.w + s3.w + bb.w;
    }
    if (t < 160) {
        float bv = bp1[t];
#pragma unroll
        for (int bi = 0; bi < 4; ++bi) {
            const float* gp = Gp + (size_t)(bg * 4 + bi) * NCOMB + 512 + t;
            float v = gp[0] + gp[SSTR] + gp[2 * SSTR] + gp[3 * SSTR] + bv;
            h1s[bi * 160 + t] = fmaxf(v, 0.f);
        }
    }
    __syncthreads();
    if (t < 160) {
        int e = t / 5, g5 = t - e * 5;
#pragma unroll
        for (int bi = 0; bi < 4; ++bi) {
            float a = bp2[t];
#pragma unroll
            for (int h = 0; h < 5; ++h)
                a += h1s[bi * 160 + e * 5 + h] * Wp2[e * 25 + h * 5 + g5];
            h2s[bi * 160 + t] = fmaxf(a, 0.f);
        }
    }
    __syncthreads();
    if (t < 128) {
        int bi = t >> 5, j = t & 31;
        float a = bp3[j];
#pragma unroll
        for (int g = 0; g < 5; ++g)
            a += h2s[bi * 160 + j * 5 + g] * Wp3[j * 5 + g];
        ps[bi * 32 + j] = a;
    }

    f32x4 o2acc = {};   // layer-2 C-frag: rows mt*16.., cols jt*16..
    for (int half = 0; half < 2; ++half) {
        __syncthreads();   // protect previous half's WzB/W2B/hB (and first-iter phase writes)
        // stage Wz half (fp32 rows 2048+k of Wep1 -> WzB[c][k], swizzled k-groups)
#pragma unroll
        for (int i = 0; i < 8; ++i) {
            int idx = i * 256 + t;                 // 2048 float4s
            int k = idx >> 6, cq = idx & 63;
            int ch = cq * 4;
            float4 v = *(const float4*)(Wep1 + (size_t)(2048 + k) * 512 + half * 256 + ch);
            int kg = k >> 3, kl = k & 7;
            WzB[(ch + 0) * 32 + (kg ^ (((ch + 0) >> 1) & 3)) * 8 + kl] = f2bf_bits(v.x);
            WzB[(ch + 1) * 32 + (kg ^ (((ch + 1) >> 1) & 3)) * 8 + kl] = f2bf_bits(v.y);
            WzB[(ch + 2) * 32 + (kg ^ (((ch + 2) >> 1) & 3)) * 8 + kl] = f2bf_bits(v.z);
            WzB[(ch + 3) * 32 + (kg ^ (((ch + 3) >> 1) & 3)) * 8 + kl] = f2bf_bits(v.w);
        }
        // stage W2 half (Wep2[c][j] -> W2B[j][c_h], swizzled c-groups)
#pragma unroll
        for (int i = 0; i < 8; ++i) {
            int idx = i * 256 + t;
            int c = idx >> 3, jq = idx & 7;
            float4 v = *(const float4*)(Wep2 + (size_t)(half * 256 + c) * 32 + jq * 4);
            int cg = c >> 3, cl = c & 7;
            W2B[(jq * 4 + 0) * 256 + (cg ^ (jq * 4 + 0)) * 8 + cl] = f2bf_bits(v.x);
            W2B[(jq * 4 + 1) * 256 + (cg ^ (jq * 4 + 1)) * 8 + cl] = f2bf_bits(v.y);
            W2B[(jq * 4 + 2) * 256 + (cg ^ (jq * 4 + 2)) * 8 + cl] = f2bf_bits(v.z);
            W2B[(jq * 4 + 3) * 256 + (cg ^ (jq * 4 + 3)) * 8 + cl] = f2bf_bits(v.w);
        }
        __syncthreads();
        // zW phase: wave -> m-tile mt, n-tiles jt*8..+8; K=32 (one MFMA each)
        short8 afz = *(const short8*)(zbf + (mt * 16 + lm) * 32 + lq * 8);
#pragma unroll
        for (int u = 0; u < 8; ++u) {
            int nt = jt * 8 + u;
            int crow = nt * 16 + lm;   // c within half (this lane's output col)
            short8 bfz = *(const short8*)(WzB + crow * 32 + (lq ^ ((crow >> 1) & 3)) * 8);
            f32x4 az = {};
            az = __builtin_amdgcn_mfma_f32_16x16x32_bf16(afz, bfz, az, 0, 0, 0);
            int cfull = half * 256 + crow;
            int cg = crow >> 3, cl = crow & 7;
#pragma unroll
            for (int r = 0; r < 4; ++r) {
                int row = mt * 16 + lq * 4 + r;
                float hv = fmaxf(hxs[(row >> 3) * 512 + cfull] + az[r], 0.f);
                hB[row * 256 + (cg ^ row) * 8 + cl] = f2bf_bits(hv);
            }
        }
        __syncthreads();
        // layer-2: o2 += h @ Wep2 over this half's K=256
        {
            int arow = mt * 16 + lm;
            int jrow = jt * 16 + lm;
#pragma unroll
            for (int ks = 0; ks < 8; ++ks) {
                int dg = ks * 4 + lq;
                short8 a2 = *(const short8*)(hB + arow * 256 + (dg ^ arow) * 8);
                short8 b2 = *(const short8*)(W2B + jrow * 256 + (dg ^ jrow) * 8);
                o2acc = __builtin_amdgcn_mfma_f32_16x16x32_bf16(a2, b2, o2acc, 0, 0, 0);
            }
        }
    }
    // epilogue: o2 C-frags -> LDS, then out[b,n] = sum_j (o2 + p) * z
#pragma unroll
    for (int r = 0; r < 4; ++r)
        o2s[(mt * 16 + lq * 4 + r) * 32 + jt * 16 + lm] = o2acc[r];
    __syncthreads();
    {
        int r = t >> 3, jg = t & 7;
        float val = 0.f;
#pragma unroll
        for (int u = 0; u < 4; ++u) {
            int j = jg * 4 + u;
            val += (o2s[r * 32 + j] + ps[(r >> 3) * 32 + j]) * zf[r * 32 + j];
        }
        val += __shfl_xor(val, 1, 64);
        val += __shfl_xor(val, 2, 64);
        val += __shfl_xor(val, 4, 64);
        if ((t & 7) == 0) out[(size_t)bg * 32 + r] = val;
    }
}

// ---------------------------------------------------------------------------
extern "C" void kernel_launch(void* const* d_in, const int* in_sizes, int n_in,
                              void* d_out, int out_size, void* d_ws, size_t ws_size,
                              hipStream_t stream) {
    const float* x    = (const float*)d_in[0];
    const float* feat = (const float*)d_in[1];
    const float* z    = (const float*)d_in[2];
    const float* Wep1 = (const float*)d_in[3];
    const float* bep1 = (const float*)d_in[4];
    const float* Wep2 = (const float*)d_in[5];
    const float* bep2 = (const float*)d_in[6];
    const float* Wp1  = (const float*)d_in[7];
    const float* bp1  = (const float*)d_in[8];
    const float* Wp2  = (const float*)d_in[9];
    const float* bp2  = (const float*)d_in[10];
    const float* Wp3  = (const float*)d_in[11];
    const float* bp3  = (const float*)d_in[12];
    float* out = (float*)d_out;
    (void)bep2;   // bep2 is zeros in setup; folded via ps? No: bep2 added below.

    char* ws  = (char*)d_ws;
    bf16* A   = (bf16*)ws;
    bf16* WT  = (bf16*)(ws + A_BYTES);
    float* Gp = (float*)(ws + A_BYTES + WT_BYTES);

    prep_a<<<4096, 256, 0, stream>>>(x, feat, A);
    prep_wt<<<2304, 256, 0, stream>>>(Wep1, Wp1, WT);
    gemm_split<<<dim3(6, 16, NSPLIT), 256, 0, stream>>>(A, WT, Gp);
    combine<<<512, 256, 0, stream>>>(Gp, z, Wep1, Wep2, bep1, bep2,
                                     bp1, Wp2, bp2, Wp3, bp3, out);
}

// Round 4
// 117.289 us; speedup vs baseline: 1.3027x; 1.0749x over previous
//
#include <hip/hip_runtime.h>
#include <hip/hip_bf16.h>

// EpiLinear: epinet (2080->512->32, z-contract) + prior ensemble (32x [1024->5->5->1], z-contract)
// B=2048, NZ=8, ND=32, STATE=HIDDEN=1024, EPI_HIDDEN=512. All inputs/outputs FP32.
//
//  - hx[b,:] = [x|feature] @ Wep1[0:2048,:] shared across the 8 z-samples -> big GEMM is
//    [2048x2048]x[2048x768] (prior layer-1 folded in as cols 512..671 of WT).
//  - GEMM: 128x128 tile, mfma 16x16x32 bf16, global_load_lds w=16, XOR LDS swizzle,
//    split-K=8 -> 768 blocks = 3/CU (uniform). m-tile on blockIdx.x (16 = 0 mod 8) so the
//    48 blocks sharing an A-stripe land on one XCD (A 1MB + WT 3MB ~ per-XCD L2).
//  - prep also emits WzT[512][32] / W2T[32][512] bf16 so combine loads its MFMA B-frags
//    straight from global (L2-resident, identical across blocks) - no per-block staging.
//  - combine: 4 b's/block (32 (b,n) rows); zW + layer-2 via MFMA; prior tail fp32 VALU.

typedef __hip_bfloat16 bf16;
typedef __attribute__((ext_vector_type(8))) short short8;   // 8 bf16 = 4 VGPRs (MFMA A/B frag)
typedef __attribute__((ext_vector_type(4))) float f32x4;    // MFMA C/D frag

#define NCOMB 768
#define NSPLIT 8
#define A_BYTES   (2048u * 2048u * 2u)
#define WT_BYTES  (768u * 2048u * 2u)
#define WZT_BYTES (512u * 32u * 2u)
#define W2T_BYTES (32u * 512u * 2u)

__device__ __forceinline__ void gload_lds16(const bf16* g, bf16* l) {
    __builtin_amdgcn_global_load_lds(
        (const __attribute__((address_space(1))) void*)g,
        (__attribute__((address_space(3))) void*)l, 16, 0, 0);
}

__device__ __forceinline__ short f2bf_bits(float f) {
    bf16 h = __float2bfloat16(f);
    return *reinterpret_cast<short*>(&h);
}

// ---------------------------------------------------------------------------
// merged prep: blocks [0,4096) A; [4096,6400) WT; [6400,6432) WzT; [6432,6464) W2T.
__global__ __launch_bounds__(256) void prep(const float* __restrict__ x,
                                            const float* __restrict__ feat,
                                            const float* __restrict__ Wep1,
                                            const float* __restrict__ Wep2,
                                            const float* __restrict__ Wp1,
                                            bf16* __restrict__ A,
                                            bf16* __restrict__ WT,
                                            bf16* __restrict__ WzT,
                                            bf16* __restrict__ W2T) {
    const int t = threadIdx.x;
    const int blk = blockIdx.x;
    if (blk < 4096) {
        // A[b][0:1024]=x[b], A[b][1024:2048]=feature[b]
        int idx = blk * 256 + t;
        int b = idx >> 9;
        int g = idx & 511;
        const float* src = (g < 256) ? (x + (size_t)b * 1024 + g * 4)
                                     : (feat + (size_t)b * 1024 + (g - 256) * 4);
        float4 v = *(const float4*)src;
        short4 p;
        p.x = f2bf_bits(v.x); p.y = f2bf_bits(v.y);
        p.z = f2bf_bits(v.z); p.w = f2bf_bits(v.w);
        *(short4*)(A + (size_t)b * 2048 + g * 4) = p;
    } else if (blk < 6400) {
        int wb = blk - 4096;
        if (wb < 256) {
            // 64x64 tiled transpose of Wep1[0:2048][0:512] -> WT[n][k]
            __shared__ short tile[64 * 66];
            int kt = wb >> 3, nt = wb & 7;
            int k0 = kt * 64, n0 = nt * 64;
            int r = t >> 4, cq = t & 15;
#pragma unroll
            for (int i = 0; i < 4; ++i) {
                int rr = r + i * 16;
                float4 v = *(const float4*)(Wep1 + (size_t)(k0 + rr) * 512 + n0 + cq * 4);
                tile[(cq * 4 + 0) * 66 + rr] = f2bf_bits(v.x);
                tile[(cq * 4 + 1) * 66 + rr] = f2bf_bits(v.y);
                tile[(cq * 4 + 2) * 66 + rr] = f2bf_bits(v.z);
                tile[(cq * 4 + 3) * 66 + rr] = f2bf_bits(v.w);
            }
            __syncthreads();
#pragma unroll
            for (int i = 0; i < 2; ++i) {
                int ch = i * 256 + t;
                int nr = ch >> 3, kc = ch & 7;
                short8 s = *(const short8*)(tile + nr * 66 + kc * 8);
                *(short8*)(WT + (size_t)(n0 + nr) * 2048 + k0 + kc * 8) = s;
            }
        } else {
            // prior cols 512..767: Wp1[e,k,h] for k<1024, else 0
            int local = (wb - 256) * 256 + t;
            int n = 512 + (local >> 11);
            int k = local & 2047;
            float v = 0.f;
            if (n < 672) {
                int q = n - 512;
                int e = q / 5, h = q - e * 5;
                if (k < 1024) v = Wp1[(size_t)e * 5120 + k * 5 + h];
            }
            WT[(size_t)n * 2048 + k] = __float2bfloat16(v);
        }
    } else if (blk < 6432) {
        // WzT[c][k] = Wep1[2048+k][c], bf16. 16384 elems.
        int local = (blk - 6400) * 256 + t;
#pragma unroll
        for (int i = 0; i < 2; ++i) {
            int e = i * 8192 + local;
            int c = e >> 5, k = e & 31;
            WzT[e] = __float2bfloat16(Wep1[(size_t)(2048 + k) * 512 + c]);
        }
    } else {
        // W2T[j][c] = Wep2[c][j], bf16. 16384 elems.
        int local = (blk - 6432) * 256 + t;
#pragma unroll
        for (int i = 0; i < 2; ++i) {
            int e = i * 8192 + local;
            int j = e >> 9, c = e & 511;
            W2T[e] = __float2bfloat16(Wep2[(size_t)c * 32 + j]);
        }
    }
}

// ---------------------------------------------------------------------------
// Gp[s][b][c] = sum_{k in split s (256 wide)} A[b][k] * WT[c][k].  grid (16, 6, 8).
__global__ __launch_bounds__(256) void gemm_split(const bf16* __restrict__ A,
                                                  const bf16* __restrict__ WT,
                                                  float* __restrict__ Gp) {
    __shared__ bf16 As[128 * 64];
    __shared__ bf16 Bs[128 * 64];
    const int t    = threadIdx.x;
    const int lane = t & 63;
    const int wv   = t >> 6;
    const int m0 = blockIdx.x * 128;          // m-tile on x: same-m blocks -> same XCD
    const int n0 = blockIdx.y * 128;
    const int kbase = blockIdx.z * 256;
    const int lm = lane & 15;
    const int lq = lane >> 4;
    const int wm = (wv & 1) * 64;
    const int wn = (wv >> 1) * 64;
    f32x4 acc[4][4] = {};

    for (int k0 = 0; k0 < 256; k0 += 64) {
        __syncthreads();
#pragma unroll
        for (int i = 0; i < 4; ++i) {
            int chunk = i * 256 + wv * 64 + lane;
            int row   = chunk >> 3;
            int gph   = chunk & 7;
            int gda   = gph ^ (row & 7);
            gload_lds16(A  + (size_t)(m0 + row) * 2048 + kbase + k0 + gda * 8,
                        As + (i * 256 + wv * 64) * 8);
            gload_lds16(WT + (size_t)(n0 + row) * 2048 + kbase + k0 + gda * 8,
                        Bs + (i * 256 + wv * 64) * 8);
        }
        __syncthreads();
#pragma unroll
        for (int kk = 0; kk < 64; kk += 32) {
            short8 af[4], bfr[4];
#pragma unroll
            for (int i2 = 0; i2 < 4; ++i2) {
                int ra = wm + i2 * 16 + lm;
                int ga = ((kk >> 3) + lq) ^ (ra & 7);
                af[i2] = *(const short8*)(As + ra * 64 + ga * 8);
                int rb = wn + i2 * 16 + lm;
                int gb = ((kk >> 3) + lq) ^ (rb & 7);
                bfr[i2] = *(const short8*)(Bs + rb * 64 + gb * 8);
            }
#pragma unroll
            for (int mi = 0; mi < 4; ++mi)
#pragma unroll
                for (int ni = 0; ni < 4; ++ni)
                    acc[mi][ni] = __builtin_amdgcn_mfma_f32_16x16x32_bf16(
                        af[mi], bfr[ni], acc[mi][ni], 0, 0, 0);
        }
    }
    // skip pad cols (>=672) and always-zero prior cols in slices 4..7 (combine won't read)
    const bool zhi = blockIdx.z >= 4;
    float* Gs = Gp + (size_t)blockIdx.z * 2048 * NCOMB;
#pragma unroll
    for (int mi = 0; mi < 4; ++mi)
#pragma unroll
        for (int ni = 0; ni < 4; ++ni) {
            int row = m0 + wm + mi * 16 + lq * 4;
            int col = n0 + wn + ni * 16 + lm;
            if (col < 672 && !(zhi && col >= 512)) {
#pragma unroll
                for (int r = 0; r < 4; ++r)
                    Gs[(size_t)(row + r) * NCOMB + col] = acc[mi][ni][r];
            }
        }
}

// ---------------------------------------------------------------------------
// combine: 512 blocks x 256 thr; block bg handles b in [bg*4, bg*4+4), rows r = bi*8+n.
__global__ __launch_bounds__(256) void combine(const float* __restrict__ Gp,
                                               const float* __restrict__ z,
                                               const bf16* __restrict__ WzT,
                                               const bf16* __restrict__ W2T,
                                               const float* __restrict__ bep1,
                                               const float* __restrict__ bep2,
                                               const float* __restrict__ bp1,
                                               const float* __restrict__ Wp2,
                                               const float* __restrict__ bp2,
                                               const float* __restrict__ Wp3,
                                               const float* __restrict__ bp3,
                                               float* __restrict__ out) {
    __shared__ float zf[1024];         // [r=32][k=32] fp32
    __shared__ short zbf[1024];        // [r][k] bf16 A-frag layout
    __shared__ float hxs[2048];        // [bi=4][c=512] split-summed + bep1
    __shared__ float h1s[640];         // [bi][160]
    __shared__ float h2s[640];
    __shared__ float ps[128];          // [bi][32]
    __shared__ short hB[32 * 512];     // [r][c] bf16, XOR-swizzled (layer-2 A-frags)
    __shared__ float o2s[1024];        // [r][j]
    const int t = threadIdx.x, bg = blockIdx.x;
    const int lane = t & 63, wv = t >> 6;
    const int lm = lane & 15, lq = lane >> 4;
    const int mt = wv & 1;             // m-tile for both MFMA phases
    const int jt = wv >> 1;
    const size_t SSTR = (size_t)2048 * NCOMB;

    // ---- phase 0: z, hx 8-slice sums, prior h1 (4 slices) ----
    {
        float4 v = *(const float4*)(z + (size_t)bg * 1024 + t * 4);
        zf[t * 4 + 0] = v.x; zf[t * 4 + 1] = v.y; zf[t * 4 + 2] = v.z; zf[t * 4 + 3] = v.w;
        zbf[t * 4 + 0] = f2bf_bits(v.x); zbf[t * 4 + 1] = f2bf_bits(v.y);
        zbf[t * 4 + 2] = f2bf_bits(v.z); zbf[t * 4 + 3] = f2bf_bits(v.w);
    }
#pragma unroll
    for (int g = 0; g < 2; ++g) {
        int q = g * 256 + t;               // 512 quads: bi(4) x cq(128)
        int bi = q >> 7, cq = q & 127;
        const float* gp = Gp + (size_t)(bg * 4 + bi) * NCOMB + cq * 4;
        float4 a4 = *(const float4*)(bep1 + cq * 4);
#pragma unroll
        for (int s = 0; s < 8; ++s) {
            float4 v = *(const float4*)(gp + (size_t)s * SSTR);
            a4.x += v.x; a4.y += v.y; a4.z += v.z; a4.w += v.w;
        }
        *(float4*)(hxs + bi * 512 + cq * 4) = a4;
    }
    if (t < 160) {
        float bv = bp1[t];
#pragma unroll
        for (int bi = 0; bi < 4; ++bi) {
            const float* gp = Gp + (size_t)(bg * 4 + bi) * NCOMB + 512 + t;
            float v = gp[0] + gp[SSTR] + gp[2 * SSTR] + gp[3 * SSTR] + bv;
            h1s[bi * 160 + t] = fmaxf(v, 0.f);
        }
    }
    __syncthreads();
    if (t < 160) {
        int e = t / 5, g5 = t - e * 5;
#pragma unroll
        for (int bi = 0; bi < 4; ++bi) {
            float a = bp2[t];
#pragma unroll
            for (int h = 0; h < 5; ++h)
                a += h1s[bi * 160 + e * 5 + h] * Wp2[e * 25 + h * 5 + g5];
            h2s[bi * 160 + t] = fmaxf(a, 0.f);
        }
    }
    __syncthreads();
    if (t < 128) {
        int bi = t >> 5, j = t & 31;
        float a = bp3[j];
#pragma unroll
        for (int g = 0; g < 5; ++g)
            a += h2s[bi * 160 + j * 5 + g] * Wp3[j * 5 + g];
        ps[bi * 32 + j] = a;
    }
    // ---- zW phase: h[r][c] = relu(hx + z@Wz), B-frags straight from global WzT ----
    short8 afz = *(const short8*)(zbf + (mt * 16 + lm) * 32 + lq * 8);
#pragma unroll
    for (int u = 0; u < 16; ++u) {
        int crow = (jt * 16 + u) * 16 + lm;          // output col in [0,512)
        short8 bfz = *(const short8*)(WzT + crow * 32 + lq * 8);
        f32x4 az = {};
        az = __builtin_amdgcn_mfma_f32_16x16x32_bf16(afz, bfz, az, 0, 0, 0);
        int cg = crow >> 3, cl = crow & 7;
#pragma unroll
        for (int r = 0; r < 4; ++r) {
            int row = mt * 16 + lq * 4 + r;
            float hv = fmaxf(hxs[(row >> 3) * 512 + crow] + az[r], 0.f);
            hB[row * 512 + ((cg ^ row)) * 8 + cl] = f2bf_bits(hv);
        }
    }
    __syncthreads();
    // ---- layer-2: o2 = h @ Wep2 (K=512), B-frags from global W2T ----
    f32x4 o2acc = {};
    {
        int arow = mt * 16 + lm;
        int jrow = jt * 16 + lm;
#pragma unroll
        for (int ks = 0; ks < 16; ++ks) {
            int dg = ks * 4 + lq;
            short8 a2 = *(const short8*)(hB + arow * 512 + (dg ^ arow) * 8);
            short8 b2 = *(const short8*)(W2T + jrow * 512 + dg * 8);
            o2acc = __builtin_amdgcn_mfma_f32_16x16x32_bf16(a2, b2, o2acc, 0, 0, 0);
        }
    }
#pragma unroll
    for (int r = 0; r < 4; ++r)
        o2s[(mt * 16 + lq * 4 + r) * 32 + jt * 16 + lm] = o2acc[r];
    __syncthreads();
    // ---- epilogue: out[b,n] = sum_j (o2 + bep2 + p) * z ----
    {
        int r = t >> 3, jg = t & 7;
        float val = 0.f;
#pragma unroll
        for (int u = 0; u < 4; ++u) {
            int j = jg * 4 + u;
            val += (o2s[r * 32 + j] + bep2[j] + ps[(r >> 3) * 32 + j]) * zf[r * 32 + j];
        }
        val += __shfl_xor(val, 1, 64);
        val += __shfl_xor(val, 2, 64);
        val += __shfl_xor(val, 4, 64);
        if ((t & 7) == 0) out[(size_t)bg * 32 + r] = val;
    }
}

// ---------------------------------------------------------------------------
extern "C" void kernel_launch(void* const* d_in, const int* in_sizes, int n_in,
                              void* d_out, int out_size, void* d_ws, size_t ws_size,
                              hipStream_t stream) {
    const float* x    = (const float*)d_in[0];
    const float* feat = (const float*)d_in[1];
    const float* z    = (const float*)d_in[2];
    const float* Wep1 = (const float*)d_in[3];
    const float* bep1 = (const float*)d_in[4];
    const float* Wep2 = (const float*)d_in[5];
    const float* bep2 = (const float*)d_in[6];
    const float* Wp1  = (const float*)d_in[7];
    const float* bp1  = (const float*)d_in[8];
    const float* Wp2  = (const float*)d_in[9];
    const float* bp2  = (const float*)d_in[10];
    const float* Wp3  = (const float*)d_in[11];
    const float* bp3  = (const float*)d_in[12];
    float* out = (float*)d_out;

    char* ws  = (char*)d_ws;
    bf16* A   = (bf16*)ws;
    bf16* WT  = (bf16*)(ws + A_BYTES);
    bf16* WzT = (bf16*)(ws + A_BYTES + WT_BYTES);
    bf16* W2T = (bf16*)(ws + A_BYTES + WT_BYTES + WZT_BYTES);
    float* Gp = (float*)(ws + A_BYTES + WT_BYTES + WZT_BYTES + W2T_BYTES);

    prep<<<6464, 256, 0, stream>>>(x, feat, Wep1, Wep2, Wp1, A, WT, WzT, W2T);
    gemm_split<<<dim3(16, 6, NSPLIT), 256, 0, stream>>>(A, WT, Gp);
    combine<<<512, 256, 0, stream>>>(Gp, z, WzT, W2T, bep1, bep2,
                                     bp1, Wp2, bp2, Wp3, bp3, out);
}